// Round 5
// baseline (299.597 us; speedup 1.0000x reference)
//
#include <hip/hip_runtime.h>

typedef __attribute__((ext_vector_type(4))) float f32x4;
typedef __attribute__((ext_vector_type(8))) __bf16 bf16x8;

__device__ __forceinline__ unsigned short f2bf(float f) {
  unsigned int u = __float_as_uint(f);
  u += 0x7FFFu + ((u >> 16) & 1u);
  return (unsigned short)(u >> 16);
}
__device__ __forceinline__ unsigned int pack2(float a, float b) {
  return (unsigned int)f2bf(a) | ((unsigned int)f2bf(b) << 16);
}

__device__ __forceinline__ void gload16(const void* g, void* l) {
  __builtin_amdgcn_global_load_lds(
      (const __attribute__((address_space(1))) void*)g,
      (__attribute__((address_space(3))) void*)l, 16, 0, 0);
}

// ---------------- weight fp32 -> bf16 ----------------
__global__ __launch_bounds__(256)
void prep_weights(const float* __restrict__ wq, const float* __restrict__ wk,
                  const float* __restrict__ wv, const float* __restrict__ wo,
                  unsigned short* __restrict__ out) {
  int i = blockIdx.x * 256 + threadIdx.x;  // 4 * 65536 total
  const float* src = (i < 65536) ? wq : (i < 131072) ? wk : (i < 196608) ? wv : wo;
  out[i] = f2bf(src[i & 65535]);
}

// ---------------- GroupNorm -> hnT [b][n][c] bf16 ----------------
__global__ __launch_bounds__(256)
void groupnorm_kernel(const float* __restrict__ x, const float* __restrict__ gamma,
                      const float* __restrict__ beta, unsigned short* __restrict__ hnT) {
  const int blk = blockIdx.x;        // b*32 + g
  const int b = blk >> 5, g = blk & 31;
  const int N = 4096;
  const float* xb = x + ((size_t)b * 256 + (size_t)g * 8) * N;
  const int tid = threadIdx.x;

  float s = 0.f, ss = 0.f;
  for (int c = 0; c < 8; ++c) {
    const float* xc = xb + (size_t)c * N;
    for (int i = tid; i < N; i += 256) { float v = xc[i]; s += v; ss += v * v; }
  }
  __shared__ float rs[4], rss[4];
  for (int m = 1; m <= 32; m <<= 1) { s += __shfl_xor(s, m); ss += __shfl_xor(ss, m); }
  const int lane = tid & 63, wid = tid >> 6;
  if (lane == 0) { rs[wid] = s; rss[wid] = ss; }
  __syncthreads();
  s  = rs[0] + rs[1] + rs[2] + rs[3];
  ss = rss[0] + rss[1] + rss[2] + rss[3];
  const float mean = s * (1.f / 32768.f);
  const float var  = ss * (1.f / 32768.f) - mean * mean;
  const float rstd = rsqrtf(var + 1e-6f);

  float gk[8], bk2[8];
  #pragma unroll
  for (int c = 0; c < 8; ++c) {
    float ga = gamma[g * 8 + c] * rstd;
    gk[c]  = ga;
    bk2[c] = beta[g * 8 + c] - mean * ga;
  }
  unsigned short* outp = hnT + (size_t)b * 256 * N + g * 8;
  for (int i = tid; i < N; i += 256) {
    union { unsigned short u[8]; uint4 v; } pk;
    #pragma unroll
    for (int c = 0; c < 8; ++c) pk.u[c] = f2bf(xb[(size_t)c * N + i] * gk[c] + bk2[c]);
    *reinterpret_cast<uint4*>(outp + (size_t)i * 256) = pk.v;
  }
}

// ---------------- fused flash attention, wave j-split ----------------
// Qt,Kt: [z][4096][256] bf16 (K-major). V: [z][256][4096] bf16 (natural).
// Ht out: [z][4096][256] bf16.
// Block: 4 waves. Wave w: q-rows q0+ (w&1)*32 .. +31, j-half (w>>1)*2048.
// KVBLK=32. Each pair (jh) double-buffers its own K/V tiles.
// End: pair-1 publishes (m,l,o) to LDS; pair-0 merges and stores.
// LDS map:
//   K slots: (jh*2+buf)*16384        [32 rows x 512B, 32 slots, slot ^= (j&7)]
//   V slots: 65536+(jh*2+buf)*16384  [256 rows x 64B, 4 slots, slot ^= (c&3)]
//   P: 131072 + w*2048               [32 rows x 64B, 4 slots, slot ^= (i&3)]
//   sc: 139264 + w*256; mArr 140288; lArr 140800.  Merge o aliases K/V area.
__global__ __launch_bounds__(256, 1)
void flash_attn(const unsigned short* __restrict__ Qt,
                const unsigned short* __restrict__ Kt,
                const unsigned short* __restrict__ Vp,
                unsigned short* __restrict__ Ht) {
  __shared__ alignas(1024) unsigned char lds[141312];
  const int tid = threadIdx.x, lane = tid & 63, w = tid >> 6;
  const int hig = lane >> 4, l15 = lane & 15;
  const int u = w & 1, jh = w >> 1;
  const int z = blockIdx.y, qtb = blockIdx.x;
  const size_t zoff = (size_t)z * 1048576;
  const unsigned short* Qz = Qt + zoff;
  const unsigned short* Kz = Kt + zoff;
  const unsigned short* Vz = Vp + zoff;
  const int q0 = qtb * 64 + u * 32;

  // Q fragments: qfr[qf][ks], B-operand (l15 = q-col, hig = c-subgroup)
  bf16x8 qfr[2][8];
  #pragma unroll
  for (int qf = 0; qf < 2; ++qf)
    #pragma unroll
    for (int ks = 0; ks < 8; ++ks)
      qfr[qf][ks] = *reinterpret_cast<const bf16x8*>(
          Qz + (size_t)(q0 + qf * 16 + l15) * 256 + ks * 32 + hig * 8);

  unsigned char* Pw = lds + 131072 + w * 2048;
  float* scp = (float*)(lds + 139264 + w * 256);

  // staging source pointers (t=0); K advances 8192 ushorts/t, V 32 ushorts/t
  const unsigned short* pK[8];
  const unsigned short* pV[8];
  {
    const int jb0 = jh * 2048;
    #pragma unroll
    for (int g = 0; g < 8; ++g) {
      const int jr = u * 16 + g * 2 + (lane >> 5);
      pK[g] = Kz + (size_t)(jb0 + jr) * 256 + (((lane & 31) ^ (jr & 7)) << 3);
      const int c = u * 128 + g * 16 + (lane >> 2);
      pV[g] = Vz + (size_t)c * 4096 + jb0 + (((lane & 3) ^ (c & 3)) << 3);
    }
  }

  auto stage = [&](int d, int t) {
    unsigned char* Kd = lds + (jh * 2 + d) * 16384 + u * 8192;
    unsigned char* Vd = lds + 65536 + (jh * 2 + d) * 16384 + u * 8192;
    #pragma unroll
    for (int g = 0; g < 8; ++g) gload16(pK[g] + (size_t)t * 8192, Kd + g * 1024);
    #pragma unroll
    for (int g = 0; g < 8; ++g) gload16(pV[g] + (size_t)t * 32, Vd + g * 1024);
  };

  f32x4 o0[16] = {}, o1[16] = {};
  float mr0 = -1e30f, mr1 = -1e30f, l0 = 0.f, l1 = 0.f;

  stage(0, 0);
  for (int t = 0; t < 64; ++t) {
    asm volatile("s_waitcnt vmcnt(0)" ::: "memory");
    __builtin_amdgcn_s_barrier();
    __builtin_amdgcn_sched_barrier(0);
    const int cur = t & 1;
    if (t + 1 < 64) stage(cur ^ 1, t + 1);

    const unsigned char* Kb = lds + (jh * 2 + cur) * 16384;
    const unsigned char* Vb = lds + 65536 + (jh * 2 + cur) * 16384;

    // QK^T swapped: sA[jf][qf] rows j=jf*16+4hig+e, col q=l15
    f32x4 sA[2][2] = {};
    #pragma unroll
    for (int ks = 0; ks < 8; ++ks) {
      #pragma unroll
      for (int jf = 0; jf < 2; ++jf) {
        const int jl = jf * 16 + l15;
        bf16x8 kf = *reinterpret_cast<const bf16x8*>(
            Kb + jl * 512 + (((4 * ks + hig) ^ (jl & 7)) << 4));
        sA[jf][0] = __builtin_amdgcn_mfma_f32_16x16x32_bf16(kf, qfr[0][ks], sA[jf][0], 0, 0, 0);
        sA[jf][1] = __builtin_amdgcn_mfma_f32_16x16x32_bf16(kf, qfr[1][ks], sA[jf][1], 0, 0, 0);
      }
    }
    float tm0 = -1e30f, tm1 = -1e30f;
    #pragma unroll
    for (int jf = 0; jf < 2; ++jf) {
      sA[jf][0] *= 0.0625f; sA[jf][1] *= 0.0625f;
      #pragma unroll
      for (int e = 0; e < 4; ++e) {
        tm0 = fmaxf(tm0, sA[jf][0][e]);
        tm1 = fmaxf(tm1, sA[jf][1][e]);
      }
    }
    tm0 = fmaxf(tm0, __shfl_xor(tm0, 16)); tm0 = fmaxf(tm0, __shfl_xor(tm0, 32));
    tm1 = fmaxf(tm1, __shfl_xor(tm1, 16)); tm1 = fmaxf(tm1, __shfl_xor(tm1, 32));
    // defer-rescale: only when running max grows (keeps P <= 1)
    if (__any((tm0 > mr0) || (tm1 > mr1))) {
      const float mn0 = fmaxf(mr0, tm0), mn1 = fmaxf(mr1, tm1);
      const float s0 = __expf(mr0 - mn0), s1 = __expf(mr1 - mn1);
      l0 *= s0; l1 *= s1;
      if (hig == 0) { scp[l15] = s0; scp[16 + l15] = s1; }
      f32x4 sv0 = *reinterpret_cast<f32x4*>(scp + hig * 4);
      f32x4 sv1 = *reinterpret_cast<f32x4*>(scp + 16 + hig * 4);
      #pragma unroll
      for (int nf = 0; nf < 16; ++nf) { o0[nf] *= sv0; o1[nf] *= sv1; }
      mr0 = mn0; mr1 = mn1;
    }
    float ts0 = 0.f, ts1 = 0.f;
    #pragma unroll
    for (int jf = 0; jf < 2; ++jf) {
      const int so = (((jf * 2 + (hig >> 1)) ^ (l15 & 3)) << 4) + ((hig & 1) << 3);
      {
        float p0 = __expf(sA[jf][0][0] - mr0), p1 = __expf(sA[jf][0][1] - mr0);
        float p2 = __expf(sA[jf][0][2] - mr0), p3 = __expf(sA[jf][0][3] - mr0);
        ts0 += (p0 + p1) + (p2 + p3);
        uint2 pk; pk.x = pack2(p0, p1); pk.y = pack2(p2, p3);
        *reinterpret_cast<uint2*>(Pw + l15 * 64 + so) = pk;
      }
      {
        float p0 = __expf(sA[jf][1][0] - mr1), p1 = __expf(sA[jf][1][1] - mr1);
        float p2 = __expf(sA[jf][1][2] - mr1), p3 = __expf(sA[jf][1][3] - mr1);
        ts1 += (p0 + p1) + (p2 + p3);
        uint2 pk; pk.x = pack2(p0, p1); pk.y = pack2(p2, p3);
        *reinterpret_cast<uint2*>(Pw + (16 + l15) * 64 + so) = pk;
      }
    }
    ts0 += __shfl_xor(ts0, 16); ts0 += __shfl_xor(ts0, 32); l0 += ts0;
    ts1 += __shfl_xor(ts1, 16); ts1 += __shfl_xor(ts1, 32); l1 += ts1;
    // PV: A = P rows i, B = V cols c, k = 32 j
    bf16x8 pa0 = *reinterpret_cast<const bf16x8*>(Pw + l15 * 64 + ((hig ^ (l15 & 3)) << 4));
    bf16x8 pa1 = *reinterpret_cast<const bf16x8*>(Pw + (16 + l15) * 64 + ((hig ^ (l15 & 3)) << 4));
    #pragma unroll
    for (int nf = 0; nf < 16; ++nf) {
      const int c = nf * 16 + l15;
      bf16x8 vb = *reinterpret_cast<const bf16x8*>(Vb + c * 64 + ((hig ^ (c & 3)) << 4));
      o0[nf] = __builtin_amdgcn_mfma_f32_16x16x32_bf16(pa0, vb, o0[nf], 0, 0, 0);
      o1[nf] = __builtin_amdgcn_mfma_f32_16x16x32_bf16(pa1, vb, o1[nf], 0, 0, 0);
    }
  }

  // ---- merge the two j-halves ----
  __syncthreads();
  float* mArr = (float*)(lds + 140288);
  float* lArr = (float*)(lds + 140800);
  if (hig == 0) {
    mArr[w * 32 + l15] = mr0; mArr[w * 32 + 16 + l15] = mr1;
    lArr[w * 32 + l15] = l0;  lArr[w * 32 + 16 + l15] = l1;
  }
  if (jh == 1) {  // publish o partials (row stride 260 f32 -> 2-way banks)
    float* oP = (float*)(lds + u * 33280);
    #pragma unroll
    for (int nf = 0; nf < 16; ++nf)
      #pragma unroll
      for (int e = 0; e < 4; ++e) {
        oP[(4 * hig + e) * 260 + nf * 16 + l15]        = o0[nf][e];
        oP[(16 + 4 * hig + e) * 260 + nf * 16 + l15]   = o1[nf][e];
      }
  }
  __syncthreads();
  if (jh == 0) {
    const float* oP = (const float*)(lds + u * 33280);
    unsigned short* Hz = Ht + zoff;
    #pragma unroll
    for (int qf = 0; qf < 2; ++qf) {
      f32x4 mA = *reinterpret_cast<const f32x4*>(mArr + w * 32 + qf * 16 + 4 * hig);
      f32x4 mB = *reinterpret_cast<const f32x4*>(mArr + (w + 2) * 32 + qf * 16 + 4 * hig);
      f32x4 lA = *reinterpret_cast<const f32x4*>(lArr + w * 32 + qf * 16 + 4 * hig);
      f32x4 lB = *reinterpret_cast<const f32x4*>(lArr + (w + 2) * 32 + qf * 16 + 4 * hig);
      f32x4 aA, aB, inv;
      #pragma unroll
      for (int e = 0; e < 4; ++e) {
        const float M = fmaxf(mA[e], mB[e]);
        const float eA = __expf(mA[e] - M), eB = __expf(mB[e] - M);
        aA[e] = eA; aB[e] = eB;
        inv[e] = 1.f / (lA[e] * eA + lB[e] * eB);
      }
      #pragma unroll
      for (int nf = 0; nf < 16; ++nf)
        #pragma unroll
        for (int e = 0; e < 4; ++e) {
          const int row = qf * 16 + 4 * hig + e;
          const float vB = oP[row * 260 + nf * 16 + l15];
          const float vA = (qf == 0) ? o0[nf][e] : o1[nf][e];
          const float val = (vA * aA[e] + vB * aB[e]) * inv[e];
          Hz[(size_t)(q0 + row) * 256 + nf * 16 + l15] = f2bf(val);
        }
    }
  }
}

// ---------------- 128x128 MFMA GEMM, A [M][K] bf16, B [N][K] bf16 ----------------
enum { MODE_T = 0, MODE_NAT = 1, MODE_OUT = 2 };

template<int MODE>
__global__ __launch_bounds__(256)
void gemm128(const unsigned short* __restrict__ A, long aStrideZ,
             const unsigned short* __restrict__ B, long bStrideZ,
             void* __restrict__ Out, long oStrideZ,
             const float* __restrict__ bias,
             const float* __restrict__ resid, long rStrideZ,
             int M, int N, int K, float scale) {
  __shared__ alignas(1024) unsigned char lds[32768];  // [buf][A 8K | B 8K]
  const int tid  = threadIdx.x;
  const int lane = tid & 63;
  const int hi   = lane >> 4;
  const int l15  = lane & 15;
  const int wid  = tid >> 6;
  const int wm = wid >> 1, wn = wid & 1;
  const int z  = blockIdx.z;
  const int m0 = blockIdx.y * 128;
  const int n0 = blockIdx.x * 128;
  const unsigned short* Az = A + (size_t)z * aStrideZ;
  const unsigned short* Bz = B + (size_t)z * bStrideZ;

  const int c0 = wid * 2, c1 = wid * 2 + 1;
  const int rr = lane >> 2;
  const int qs = (lane & 3) ^ ((lane >> 3) & 3);
  const unsigned short* pa0 = Az + (size_t)(m0 + c0 * 16 + rr) * K + qs * 8;
  const unsigned short* pa1 = Az + (size_t)(m0 + c1 * 16 + rr) * K + qs * 8;
  const unsigned short* pb0 = Bz + (size_t)(n0 + c0 * 16 + rr) * K + qs * 8;
  const unsigned short* pb1 = Bz + (size_t)(n0 + c1 * 16 + rr) * K + qs * 8;
  unsigned char* lA0 = lds + c0 * 1024;
  unsigned char* lA1 = lds + c1 * 1024;
  unsigned char* lB0 = lds + 8192 + c0 * 1024;
  unsigned char* lB1 = lds + 8192 + c1 * 1024;

  const int slot = hi ^ ((l15 >> 1) & 3);
  int roffA[4], roffB[4];
  #pragma unroll
  for (int t = 0; t < 4; ++t) {
    roffA[t] = (wm * 64 + t * 16 + l15) * 64 + slot * 16;
    roffB[t] = 8192 + (wn * 64 + t * 16 + l15) * 64 + slot * 16;
  }

  f32x4 acc[4][4] = {};

  const int nk = K >> 5;
  gload16(pa0, lA0); gload16(pa1, lA1);
  gload16(pb0, lB0); gload16(pb1, lB1);
  __syncthreads();

  int cur = 0;
  for (int kt = 0; kt < nk; ++kt) {
    if (kt + 1 < nk) {
      const size_t ko = (size_t)(kt + 1) * 32;
      const int bo = (cur ^ 1) * 16384;
      gload16(pa0 + ko, lA0 + bo); gload16(pa1 + ko, lA1 + bo);
      gload16(pb0 + ko, lB0 + bo); gload16(pb1 + ko, lB1 + bo);
    }
    const unsigned char* base = lds + cur * 16384;
    bf16x8 af[4], bfr[4];
    #pragma unroll
    for (int t = 0; t < 4; ++t) {
      af[t]  = *reinterpret_cast<const bf16x8*>(base + roffA[t]);
      bfr[t] = *reinterpret_cast<const bf16x8*>(base + roffB[t]);
    }
    #pragma unroll
    for (int mt = 0; mt < 4; ++mt)
      #pragma unroll
      for (int nt = 0; nt < 4; ++nt)
        acc[mt][nt] = __builtin_amdgcn_mfma_f32_16x16x32_bf16(af[mt], bfr[nt], acc[mt][nt], 0, 0, 0);
    __syncthreads();
    cur ^= 1;
  }

  const int gmb = m0 + wm * 64;
  const int gnb = n0 + wn * 64;
  if constexpr (MODE == MODE_T) {
    unsigned short* O = (unsigned short*)Out + (size_t)z * oStrideZ;
    #pragma unroll
    for (int mt = 0; mt < 4; ++mt) {
      const int gm0 = gmb + mt * 16 + 4 * hi;
      const float b0 = bias[gm0], b1 = bias[gm0 + 1], b2 = bias[gm0 + 2], b3 = bias[gm0 + 3];
      #pragma unroll
      for (int nt = 0; nt < 4; ++nt) {
        const int gn = gnb + nt * 16 + l15;
        ushort4 pk;
        pk.x = f2bf(acc[mt][nt][0] + b0);
        pk.y = f2bf(acc[mt][nt][1] + b1);
        pk.z = f2bf(acc[mt][nt][2] + b2);
        pk.w = f2bf(acc[mt][nt][3] + b3);
        *reinterpret_cast<ushort4*>(O + (size_t)gn * M + gm0) = pk;
      }
    }
  } else if constexpr (MODE == MODE_NAT) {
    unsigned short* O = (unsigned short*)Out + (size_t)z * oStrideZ;
    #pragma unroll
    for (int mt = 0; mt < 4; ++mt) {
      const int gm0 = gmb + mt * 16 + 4 * hi;
      #pragma unroll
      for (int nt = 0; nt < 4; ++nt) {
        const int gn = gnb + nt * 16 + l15;
        #pragma unroll
        for (int e = 0; e < 4; ++e) {
          float v = acc[mt][nt][e] * scale + (bias ? bias[gm0 + e] : 0.f);
          O[(size_t)(gm0 + e) * N + gn] = f2bf(v);
        }
      }
    }
  } else {
    float* O = (float*)Out + (size_t)z * oStrideZ;
    const float* R = resid + (size_t)z * rStrideZ;
    #pragma unroll
    for (int mt = 0; mt < 4; ++mt) {
      const int gm0 = gmb + mt * 16 + 4 * hi;
      #pragma unroll
      for (int nt = 0; nt < 4; ++nt) {
        const int gn = gnb + nt * 16 + l15;
        #pragma unroll
        for (int e = 0; e < 4; ++e) {
          size_t idx = (size_t)(gm0 + e) * N + gn;
          O[idx] = acc[mt][nt][e] + bias[gm0 + e] + R[idx];
        }
      }
    }
  }
}

__global__ void ws_too_small(float* out, float v) {
  if (threadIdx.x == 0 && blockIdx.x == 0) out[0] = v;
}

extern "C" void kernel_launch(void* const* d_in, const int* in_sizes, int n_in,
                              void* d_out, int out_size, void* d_ws, size_t ws_size,
                              hipStream_t stream) {
  const float* x     = (const float*)d_in[0];
  const float* gamma = (const float*)d_in[1];
  const float* beta  = (const float*)d_in[2];
  const float* Wq    = (const float*)d_in[3];
  const float* bq    = (const float*)d_in[4];
  const float* Wk    = (const float*)d_in[5];
  const float* bk    = (const float*)d_in[6];
  const float* Wv    = (const float*)d_in[7];
  const float* bv    = (const float*)d_in[8];
  const float* Wo    = (const float*)d_in[9];
  const float* bo    = (const float*)d_in[10];
  float* out = (float*)d_out;

  unsigned char* ws = (unsigned char*)d_ws;
  unsigned short* WB  = (unsigned short*)(ws);             // [4][256][256] bf16 (q,k,v,o)
  unsigned short* hnT = (unsigned short*)(ws + 524288);    // [4][4096][256]
  unsigned short* Qt  = (unsigned short*)(ws + 8912896);   // [4][4096][256]
  unsigned short* Kt  = (unsigned short*)(ws + 17301504);  // [4][4096][256]
  unsigned short* V   = (unsigned short*)(ws + 25690112);  // [4][256][4096]
  unsigned short* Ht  = (unsigned short*)(ws + 34078720);  // [4][4096][256]

  if (ws_size < 42467328) {
    hipMemsetAsync(d_out, 0, (size_t)out_size * 4, stream);
    ws_too_small<<<1, 64, 0, stream>>>(out, (float)ws_size);
    return;
  }

  prep_weights<<<1024, 256, 0, stream>>>(Wq, Wk, Wv, Wo, WB);
  groupnorm_kernel<<<128, 256, 0, stream>>>(x, gamma, beta, hnT);

  // QKV projections: M=256 (c_out), N=4096 (pixels), K=256 (c_in); z = batch
  gemm128<MODE_T><<<dim3(32, 2, 4), 256, 0, stream>>>(
      WB, 0, hnT, 1048576, Qt, 1048576, bq, nullptr, 0, 256, 4096, 256, 1.f);
  gemm128<MODE_T><<<dim3(32, 2, 4), 256, 0, stream>>>(
      WB + 65536, 0, hnT, 1048576, Kt, 1048576, bk, nullptr, 0, 256, 4096, 256, 1.f);
  gemm128<MODE_NAT><<<dim3(32, 2, 4), 256, 0, stream>>>(
      WB + 131072, 0, hnT, 1048576, V, 1048576, bv, nullptr, 0, 256, 4096, 256, 1.f);

  // fused attention
  flash_attn<<<dim3(64, 4), 256, 0, stream>>>(Qt, Kt, V, Ht);

  // out[co][n] = sum_c Wo[co][c] * Ht[n][c] + bo[co] + x;  M=256, N=4096, K=256
  gemm128<MODE_OUT><<<dim3(32, 2, 4), 256, 0, stream>>>(
      WB + 196608, 0, Ht, 1048576, out, 1048576, bo, x, 1048576, 256, 4096, 256, 1.f);
}

// Round 6
// 257.853 us; speedup vs baseline: 1.1619x; 1.1619x over previous
//
#include <hip/hip_runtime.h>

typedef __attribute__((ext_vector_type(4))) float f32x4;
typedef __attribute__((ext_vector_type(8))) __bf16 bf16x8;

__device__ __forceinline__ unsigned short f2bf(float f) {
  unsigned int u = __float_as_uint(f);
  u += 0x7FFFu + ((u >> 16) & 1u);
  return (unsigned short)(u >> 16);
}
__device__ __forceinline__ unsigned int pack2(float a, float b) {
  return (unsigned int)f2bf(a) | ((unsigned int)f2bf(b) << 16);
}

__device__ __forceinline__ void gload16(const void* g, void* l) {
  __builtin_amdgcn_global_load_lds(
      (const __attribute__((address_space(1))) void*)g,
      (__attribute__((address_space(3))) void*)l, 16, 0, 0);
}

// ---------------- weight fp32 -> bf16 ----------------
__global__ __launch_bounds__(256)
void prep_weights(const float* __restrict__ wq, const float* __restrict__ wk,
                  const float* __restrict__ wv, const float* __restrict__ wo,
                  unsigned short* __restrict__ out) {
  int i = blockIdx.x * 256 + threadIdx.x;  // 4 * 65536 total
  const float* src = (i < 65536) ? wq : (i < 131072) ? wk : (i < 196608) ? wv : wo;
  out[i] = f2bf(src[i & 65535]);
}

// ---------------- GroupNorm -> hnT [b][n][c] bf16 ----------------
__global__ __launch_bounds__(256)
void groupnorm_kernel(const float* __restrict__ x, const float* __restrict__ gamma,
                      const float* __restrict__ beta, unsigned short* __restrict__ hnT) {
  const int blk = blockIdx.x;        // b*32 + g
  const int b = blk >> 5, g = blk & 31;
  const int N = 4096;
  const float* xb = x + ((size_t)b * 256 + (size_t)g * 8) * N;
  const int tid = threadIdx.x;

  float s = 0.f, ss = 0.f;
  for (int c = 0; c < 8; ++c) {
    const float* xc = xb + (size_t)c * N;
    for (int i = tid; i < N; i += 256) { float v = xc[i]; s += v; ss += v * v; }
  }
  __shared__ float rs[4], rss[4];
  for (int m = 1; m <= 32; m <<= 1) { s += __shfl_xor(s, m); ss += __shfl_xor(ss, m); }
  const int lane = tid & 63, wid = tid >> 6;
  if (lane == 0) { rs[wid] = s; rss[wid] = ss; }
  __syncthreads();
  s  = rs[0] + rs[1] + rs[2] + rs[3];
  ss = rss[0] + rss[1] + rss[2] + rss[3];
  const float mean = s * (1.f / 32768.f);
  const float var  = ss * (1.f / 32768.f) - mean * mean;
  const float rstd = rsqrtf(var + 1e-6f);

  float gk[8], bk2[8];
  #pragma unroll
  for (int c = 0; c < 8; ++c) {
    float ga = gamma[g * 8 + c] * rstd;
    gk[c]  = ga;
    bk2[c] = beta[g * 8 + c] - mean * ga;
  }
  unsigned short* outp = hnT + (size_t)b * 256 * N + g * 8;
  for (int i = tid; i < N; i += 256) {
    union { unsigned short u[8]; uint4 v; } pk;
    #pragma unroll
    for (int c = 0; c < 8; ++c) pk.u[c] = f2bf(xb[(size_t)c * N + i] * gk[c] + bk2[c]);
    *reinterpret_cast<uint4*>(outp + (size_t)i * 256) = pk.v;
  }
}

// ---------------- fused flash attention, block j-split ----------------
// Grid (qtb=32, jh=2, z=4). Block: 4 waves, wave w owns q-rows q0=qtb*128+w*32
// .. +31. Each block processes j in [jh*2048, jh*2048+2048), KVBLK=64.
// Round-4 LDS geometry (all 2-way-conflict-free):
//   K bufs @0,@32768: 64 rows x 512B, slot ^= (j&7)
//   V bufs @65536,@98304: 256 rows x 128B, slot ^= (c&7)
//   P @131072 + w*4096: 32 rows x 128B, slot ^= (row&7)
//   sc @147456 + w*128 (32 f32)
// Partials (un-normalized o, running m, sum l) written to global; a separate
// merge kernel combines the two j-halves.
__global__ __launch_bounds__(256, 1)
void flash_attn(const unsigned short* __restrict__ Qt,
                const unsigned short* __restrict__ Kt,
                const unsigned short* __restrict__ Vp,
                float* __restrict__ Opart, float* __restrict__ mpart,
                float* __restrict__ lpart) {
  __shared__ alignas(1024) unsigned char lds[147968];
  const int tid = threadIdx.x, lane = tid & 63, w = tid >> 6;
  const int hig = lane >> 4, l15 = lane & 15;
  const int qtb = blockIdx.x, jh = blockIdx.y, z = blockIdx.z;
  const size_t zoff = (size_t)z * 1048576;
  const unsigned short* Qz = Qt + zoff;
  const unsigned short* Kz = Kt + zoff;
  const unsigned short* Vz = Vp + zoff;
  const int q0 = qtb * 128 + w * 32;
  const int jb0 = jh * 2048;

  // Q fragments: qfr[qf][ks], B-operand (l15 = q-col, hig = c-subgroup)
  bf16x8 qfr[2][8];
  #pragma unroll
  for (int qf = 0; qf < 2; ++qf)
    #pragma unroll
    for (int ks = 0; ks < 8; ++ks)
      qfr[qf][ks] = *reinterpret_cast<const bf16x8*>(
          Qz + (size_t)(q0 + qf * 16 + l15) * 256 + ks * 32 + hig * 8);

  unsigned char* Pw = lds + 131072 + w * 4096;
  float* scp = (float*)(lds + 147456 + w * 128);

  // staging source pointers (t=0); K advances 16384 ushorts/t, V 64/t
  const unsigned short* pK[8];
  const unsigned short* pV[8];
  #pragma unroll
  for (int g = 0; g < 8; ++g) {
    const int jr = w * 16 + g * 2 + (lane >> 5);
    pK[g] = Kz + (size_t)(jb0 + jr) * 256 + (((lane & 31) ^ (jr & 7)) << 3);
    const int cV = w * 64 + g * 8 + (lane >> 3);
    pV[g] = Vz + (size_t)cV * 4096 + jb0 + (((lane & 7) ^ (cV & 7)) << 3);
  }

  auto stage = [&](int d, int t) {
    unsigned char* Kd = lds + d * 32768 + w * 8192;
    unsigned char* Vd = lds + 65536 + d * 32768 + w * 8192;
    #pragma unroll
    for (int g = 0; g < 8; ++g) gload16(pK[g] + (size_t)t * 16384, Kd + g * 1024);
    #pragma unroll
    for (int g = 0; g < 8; ++g) gload16(pV[g] + (size_t)t * 64, Vd + g * 1024);
  };

  f32x4 o0[16] = {}, o1[16] = {};
  float mr0 = -1e30f, mr1 = -1e30f, l0 = 0.f, l1 = 0.f;

  stage(0, 0);
  for (int t = 0; t < 32; ++t) {
    asm volatile("s_waitcnt vmcnt(0)" ::: "memory");
    __builtin_amdgcn_s_barrier();
    __builtin_amdgcn_sched_barrier(0);
    const int cur = t & 1;
    if (t + 1 < 32) stage(cur ^ 1, t + 1);

    const unsigned char* Kb = lds + cur * 32768;
    const unsigned char* Vb = lds + 65536 + cur * 32768;

    // QK^T swapped: sA[jf][qf] rows j=jf*16+4hig+e, col q=l15
    f32x4 sA[4][2] = {};
    #pragma unroll
    for (int ks = 0; ks < 8; ++ks) {
      #pragma unroll
      for (int jf = 0; jf < 4; ++jf) {
        const int jl = jf * 16 + l15;
        bf16x8 kf = *reinterpret_cast<const bf16x8*>(
            Kb + jl * 512 + (((4 * ks + hig) ^ (jl & 7)) << 4));
        sA[jf][0] = __builtin_amdgcn_mfma_f32_16x16x32_bf16(kf, qfr[0][ks], sA[jf][0], 0, 0, 0);
        sA[jf][1] = __builtin_amdgcn_mfma_f32_16x16x32_bf16(kf, qfr[1][ks], sA[jf][1], 0, 0, 0);
      }
    }
    float tm0 = -1e30f, tm1 = -1e30f;
    #pragma unroll
    for (int jf = 0; jf < 4; ++jf) {
      sA[jf][0] *= 0.0625f; sA[jf][1] *= 0.0625f;
      #pragma unroll
      for (int e = 0; e < 4; ++e) {
        tm0 = fmaxf(tm0, sA[jf][0][e]);
        tm1 = fmaxf(tm1, sA[jf][1][e]);
      }
    }
    tm0 = fmaxf(tm0, __shfl_xor(tm0, 16)); tm0 = fmaxf(tm0, __shfl_xor(tm0, 32));
    tm1 = fmaxf(tm1, __shfl_xor(tm1, 16)); tm1 = fmaxf(tm1, __shfl_xor(tm1, 32));
    // defer-rescale: only when running max grows (keeps P <= 1)
    if (__any((tm0 > mr0) || (tm1 > mr1))) {
      const float mn0 = fmaxf(mr0, tm0), mn1 = fmaxf(mr1, tm1);
      const float s0 = __expf(mr0 - mn0), s1 = __expf(mr1 - mn1);
      l0 *= s0; l1 *= s1;
      if (hig == 0) { scp[l15] = s0; scp[16 + l15] = s1; }
      f32x4 sv0 = *reinterpret_cast<f32x4*>(scp + hig * 4);
      f32x4 sv1 = *reinterpret_cast<f32x4*>(scp + 16 + hig * 4);
      #pragma unroll
      for (int nf = 0; nf < 16; ++nf) { o0[nf] *= sv0; o1[nf] *= sv1; }
      mr0 = mn0; mr1 = mn1;
    }
    float ts0 = 0.f, ts1 = 0.f;
    #pragma unroll
    for (int jf = 0; jf < 4; ++jf) {
      const int so = (((2 * jf + (hig >> 1)) ^ (l15 & 7)) << 4) + ((hig & 1) << 3);
      {
        float p0 = __expf(sA[jf][0][0] - mr0), p1 = __expf(sA[jf][0][1] - mr0);
        float p2 = __expf(sA[jf][0][2] - mr0), p3 = __expf(sA[jf][0][3] - mr0);
        ts0 += (p0 + p1) + (p2 + p3);
        uint2 pk; pk.x = pack2(p0, p1); pk.y = pack2(p2, p3);
        *reinterpret_cast<uint2*>(Pw + l15 * 128 + so) = pk;
      }
      {
        float p0 = __expf(sA[jf][1][0] - mr1), p1 = __expf(sA[jf][1][1] - mr1);
        float p2 = __expf(sA[jf][1][2] - mr1), p3 = __expf(sA[jf][1][3] - mr1);
        ts1 += (p0 + p1) + (p2 + p3);
        uint2 pk; pk.x = pack2(p0, p1); pk.y = pack2(p2, p3);
        *reinterpret_cast<uint2*>(Pw + (16 + l15) * 128 + so) = pk;
      }
    }
    ts0 += __shfl_xor(ts0, 16); ts0 += __shfl_xor(ts0, 32); l0 += ts0;
    ts1 += __shfl_xor(ts1, 16); ts1 += __shfl_xor(ts1, 32); l1 += ts1;
    // PV: A = P rows i, B = V cols c, k = 64 j (2 chunks of 32)
    #pragma unroll
    for (int ks = 0; ks < 2; ++ks) {
      bf16x8 pa0 = *reinterpret_cast<const bf16x8*>(
          Pw + l15 * 128 + (((4 * ks + hig) ^ (l15 & 7)) << 4));
      bf16x8 pa1 = *reinterpret_cast<const bf16x8*>(
          Pw + (16 + l15) * 128 + (((4 * ks + hig) ^ (l15 & 7)) << 4));
      #pragma unroll
      for (int nf = 0; nf < 16; ++nf) {
        const int c = nf * 16 + l15;
        bf16x8 vb = *reinterpret_cast<const bf16x8*>(
            Vb + c * 128 + (((4 * ks + hig) ^ (c & 7)) << 4));
        o0[nf] = __builtin_amdgcn_mfma_f32_16x16x32_bf16(pa0, vb, o0[nf], 0, 0, 0);
        o1[nf] = __builtin_amdgcn_mfma_f32_16x16x32_bf16(pa1, vb, o1[nf], 0, 0, 0);
      }
    }
  }

  // epilogue: write un-normalized partials + m,l for the merge kernel
  const size_t pb = ((size_t)(jh * 4 + z) * 4096 + q0) * 256;
  #pragma unroll
  for (int qf = 0; qf < 2; ++qf)
    #pragma unroll
    for (int nf = 0; nf < 16; ++nf)
      #pragma unroll
      for (int e = 0; e < 4; ++e) {
        const int row = qf * 16 + 4 * hig + e;
        Opart[pb + (size_t)row * 256 + nf * 16 + l15] = (qf == 0) ? o0[nf][e] : o1[nf][e];
      }
  if (hig == 0) {
    const size_t mb = (size_t)(jh * 4 + z) * 4096 + q0;
    mpart[mb + l15] = mr0; mpart[mb + 16 + l15] = mr1;
    lpart[mb + l15] = l0;  lpart[mb + 16 + l15] = l1;
  }
}

// ---------------- merge the two j-halves -> Ht bf16 ----------------
__global__ __launch_bounds__(256)
void flash_merge(const float* __restrict__ Opart, const float* __restrict__ mpart,
                 const float* __restrict__ lpart, unsigned short* __restrict__ Ht) {
  const int t = threadIdx.x;
  const int r = blockIdx.x * 4 + (t >> 6);   // r = z*4096 + n, in [0,16384)
  const int c = (t & 63) * 4;
  const int z = r >> 12, n = r & 4095;
  const int iA = z * 4096 + n;               // jh = 0
  const int iB = (4 + z) * 4096 + n;         // jh = 1
  const float mA = mpart[iA], mB = mpart[iB];
  const float M = fmaxf(mA, mB);
  const float aA = __expf(mA - M), aB = __expf(mB - M);
  const float inv = 1.f / (lpart[iA] * aA + lpart[iB] * aB);
  f32x4 vA = *reinterpret_cast<const f32x4*>(Opart + (size_t)iA * 256 + c);
  f32x4 vB = *reinterpret_cast<const f32x4*>(Opart + (size_t)iB * 256 + c);
  ushort4 pk;
  pk.x = f2bf((vA[0] * aA + vB[0] * aB) * inv);
  pk.y = f2bf((vA[1] * aA + vB[1] * aB) * inv);
  pk.z = f2bf((vA[2] * aA + vB[2] * aB) * inv);
  pk.w = f2bf((vA[3] * aA + vB[3] * aB) * inv);
  *reinterpret_cast<ushort4*>(Ht + (size_t)r * 256 + c) = pk;
}

// ---------------- 128x128 MFMA GEMM, A [M][K] bf16, B [N][K] bf16 ----------------
enum { MODE_T = 0, MODE_NAT = 1, MODE_OUT = 2 };

template<int MODE>
__global__ __launch_bounds__(256)
void gemm128(const unsigned short* __restrict__ A, long aStrideZ,
             const unsigned short* __restrict__ B, long bStrideZ,
             void* __restrict__ Out, long oStrideZ,
             const float* __restrict__ bias,
             const float* __restrict__ resid, long rStrideZ,
             int M, int N, int K, float scale) {
  __shared__ alignas(1024) unsigned char lds[32768];  // [buf][A 8K | B 8K]
  const int tid  = threadIdx.x;
  const int lane = tid & 63;
  const int hi   = lane >> 4;
  const int l15  = lane & 15;
  const int wid  = tid >> 6;
  const int wm = wid >> 1, wn = wid & 1;
  const int z  = blockIdx.z;
  const int m0 = blockIdx.y * 128;
  const int n0 = blockIdx.x * 128;
  const unsigned short* Az = A + (size_t)z * aStrideZ;
  const unsigned short* Bz = B + (size_t)z * bStrideZ;

  const int c0 = wid * 2, c1 = wid * 2 + 1;
  const int rr = lane >> 2;
  const int qs = (lane & 3) ^ ((lane >> 3) & 3);
  const unsigned short* pa0 = Az + (size_t)(m0 + c0 * 16 + rr) * K + qs * 8;
  const unsigned short* pa1 = Az + (size_t)(m0 + c1 * 16 + rr) * K + qs * 8;
  const unsigned short* pb0 = Bz + (size_t)(n0 + c0 * 16 + rr) * K + qs * 8;
  const unsigned short* pb1 = Bz + (size_t)(n0 + c1 * 16 + rr) * K + qs * 8;
  unsigned char* lA0 = lds + c0 * 1024;
  unsigned char* lA1 = lds + c1 * 1024;
  unsigned char* lB0 = lds + 8192 + c0 * 1024;
  unsigned char* lB1 = lds + 8192 + c1 * 1024;

  const int slot = hi ^ ((l15 >> 1) & 3);
  int roffA[4], roffB[4];
  #pragma unroll
  for (int t = 0; t < 4; ++t) {
    roffA[t] = (wm * 64 + t * 16 + l15) * 64 + slot * 16;
    roffB[t] = 8192 + (wn * 64 + t * 16 + l15) * 64 + slot * 16;
  }

  f32x4 acc[4][4] = {};

  const int nk = K >> 5;
  gload16(pa0, lA0); gload16(pa1, lA1);
  gload16(pb0, lB0); gload16(pb1, lB1);
  __syncthreads();

  int cur = 0;
  for (int kt = 0; kt < nk; ++kt) {
    if (kt + 1 < nk) {
      const size_t ko = (size_t)(kt + 1) * 32;
      const int bo = (cur ^ 1) * 16384;
      gload16(pa0 + ko, lA0 + bo); gload16(pa1 + ko, lA1 + bo);
      gload16(pb0 + ko, lB0 + bo); gload16(pb1 + ko, lB1 + bo);
    }
    const unsigned char* base = lds + cur * 16384;
    bf16x8 af[4], bfr[4];
    #pragma unroll
    for (int t = 0; t < 4; ++t) {
      af[t]  = *reinterpret_cast<const bf16x8*>(base + roffA[t]);
      bfr[t] = *reinterpret_cast<const bf16x8*>(base + roffB[t]);
    }
    #pragma unroll
    for (int mt = 0; mt < 4; ++mt)
      #pragma unroll
      for (int nt = 0; nt < 4; ++nt)
        acc[mt][nt] = __builtin_amdgcn_mfma_f32_16x16x32_bf16(af[mt], bfr[nt], acc[mt][nt], 0, 0, 0);
    __syncthreads();
    cur ^= 1;
  }

  const int gmb = m0 + wm * 64;
  const int gnb = n0 + wn * 64;
  if constexpr (MODE == MODE_T) {
    unsigned short* O = (unsigned short*)Out + (size_t)z * oStrideZ;
    #pragma unroll
    for (int mt = 0; mt < 4; ++mt) {
      const int gm0 = gmb + mt * 16 + 4 * hi;
      const float b0 = bias[gm0], b1 = bias[gm0 + 1], b2 = bias[gm0 + 2], b3 = bias[gm0 + 3];
      #pragma unroll
      for (int nt = 0; nt < 4; ++nt) {
        const int gn = gnb + nt * 16 + l15;
        ushort4 pk;
        pk.x = f2bf(acc[mt][nt][0] + b0);
        pk.y = f2bf(acc[mt][nt][1] + b1);
        pk.z = f2bf(acc[mt][nt][2] + b2);
        pk.w = f2bf(acc[mt][nt][3] + b3);
        *reinterpret_cast<ushort4*>(O + (size_t)gn * M + gm0) = pk;
      }
    }
  } else if constexpr (MODE == MODE_NAT) {
    unsigned short* O = (unsigned short*)Out + (size_t)z * oStrideZ;
    #pragma unroll
    for (int mt = 0; mt < 4; ++mt) {
      const int gm0 = gmb + mt * 16 + 4 * hi;
      #pragma unroll
      for (int nt = 0; nt < 4; ++nt) {
        const int gn = gnb + nt * 16 + l15;
        #pragma unroll
        for (int e = 0; e < 4; ++e) {
          float v = acc[mt][nt][e] * scale + (bias ? bias[gm0 + e] : 0.f);
          O[(size_t)(gm0 + e) * N + gn] = f2bf(v);
        }
      }
    }
  } else {
    float* O = (float*)Out + (size_t)z * oStrideZ;
    const float* R = resid + (size_t)z * rStrideZ;
    #pragma unroll
    for (int mt = 0; mt < 4; ++mt) {
      const int gm0 = gmb + mt * 16 + 4 * hi;
      #pragma unroll
      for (int nt = 0; nt < 4; ++nt) {
        const int gn = gnb + nt * 16 + l15;
        #pragma unroll
        for (int e = 0; e < 4; ++e) {
          size_t idx = (size_t)(gm0 + e) * N + gn;
          O[idx] = acc[mt][nt][e] + bias[gm0 + e] + R[idx];
        }
      }
    }
  }
}

__global__ void ws_too_small(float* out, float v) {
  if (threadIdx.x == 0 && blockIdx.x == 0) out[0] = v;
}

extern "C" void kernel_launch(void* const* d_in, const int* in_sizes, int n_in,
                              void* d_out, int out_size, void* d_ws, size_t ws_size,
                              hipStream_t stream) {
  const float* x     = (const float*)d_in[0];
  const float* gamma = (const float*)d_in[1];
  const float* beta  = (const float*)d_in[2];
  const float* Wq    = (const float*)d_in[3];
  const float* bq    = (const float*)d_in[4];
  const float* Wk    = (const float*)d_in[5];
  const float* bk    = (const float*)d_in[6];
  const float* Wv    = (const float*)d_in[7];
  const float* bv    = (const float*)d_in[8];
  const float* Wo    = (const float*)d_in[9];
  const float* bo    = (const float*)d_in[10];
  float* out = (float*)d_out;

  unsigned char* ws = (unsigned char*)d_ws;
  unsigned short* WB    = (unsigned short*)(ws);             // [4][256][256] bf16 (q,k,v,o)
  unsigned short* hnT   = (unsigned short*)(ws + 524288);    // [4][4096][256]
  unsigned short* Qt    = (unsigned short*)(ws + 8912896);   // [4][4096][256]
  unsigned short* Kt    = (unsigned short*)(ws + 17301504);  // [4][4096][256]
  unsigned short* V     = (unsigned short*)(ws + 25690112);  // [4][256][4096]
  unsigned short* Ht    = (unsigned short*)(ws + 34078720);  // [4][4096][256]
  float*          Opart = (float*)(ws + 42467328);           // [2][4][4096][256]
  float*          mpart = (float*)(ws + 76021760);           // [2][4][4096]
  float*          lpart = (float*)(ws + 76152832);           // [2][4][4096]

  if (ws_size < 76283904) {
    hipMemsetAsync(d_out, 0, (size_t)out_size * 4, stream);
    ws_too_small<<<1, 64, 0, stream>>>(out, (float)ws_size);
    return;
  }

  prep_weights<<<1024, 256, 0, stream>>>(Wq, Wk, Wv, Wo, WB);
  groupnorm_kernel<<<128, 256, 0, stream>>>(x, gamma, beta, hnT);

  // QKV projections: M=256 (c_out), N=4096 (pixels), K=256 (c_in); z = batch
  gemm128<MODE_T><<<dim3(32, 2, 4), 256, 0, stream>>>(
      WB, 0, hnT, 1048576, Qt, 1048576, bq, nullptr, 0, 256, 4096, 256, 1.f);
  gemm128<MODE_T><<<dim3(32, 2, 4), 256, 0, stream>>>(
      WB + 65536, 0, hnT, 1048576, Kt, 1048576, bk, nullptr, 0, 256, 4096, 256, 1.f);
  gemm128<MODE_NAT><<<dim3(32, 2, 4), 256, 0, stream>>>(
      WB + 131072, 0, hnT, 1048576, V, 1048576, bv, nullptr, 0, 256, 4096, 256, 1.f);

  // fused attention, j split across blocks; then merge the two halves
  flash_attn<<<dim3(32, 2, 4), 256, 0, stream>>>(Qt, Kt, V, Opart, mpart, lpart);
  flash_merge<<<4096, 256, 0, stream>>>(Opart, mpart, lpart, Ht);

  // out[co][n] = sum_c Wo[co][c] * Ht[n][c] + bo[co] + x;  M=256, N=4096, K=256
  gemm128<MODE_OUT><<<dim3(32, 2, 4), 256, 0, stream>>>(
      WB + 196608, 0, Ht, 1048576, out, 1048576, bo, x, 1048576, 256, 4096, 256, 1.f);
}

// Round 7
// 248.690 us; speedup vs baseline: 1.2047x; 1.0368x over previous
//
#include <hip/hip_runtime.h>

typedef __attribute__((ext_vector_type(4))) float f32x4;
typedef __attribute__((ext_vector_type(8))) __bf16 bf16x8;

__device__ __forceinline__ unsigned short f2bf(float f) {
  unsigned int u = __float_as_uint(f);
  u += 0x7FFFu + ((u >> 16) & 1u);
  return (unsigned short)(u >> 16);
}
__device__ __forceinline__ unsigned int pack2(float a, float b) {
  return (unsigned int)f2bf(a) | ((unsigned int)f2bf(b) << 16);
}
__device__ __forceinline__ float bf2f(unsigned short u) {
  return __uint_as_float(((unsigned int)u) << 16);
}

__device__ __forceinline__ void gload16(const void* g, void* l) {
  __builtin_amdgcn_global_load_lds(
      (const __attribute__((address_space(1))) void*)g,
      (__attribute__((address_space(3))) void*)l, 16, 0, 0);
}

// ---------------- weight fp32 -> bf16 ----------------
__global__ __launch_bounds__(256)
void prep_weights(const float* __restrict__ wq, const float* __restrict__ wk,
                  const float* __restrict__ wv, const float* __restrict__ wo,
                  unsigned short* __restrict__ out) {
  int i = blockIdx.x * 256 + threadIdx.x;  // 4 * 65536 total
  const float* src = (i < 65536) ? wq : (i < 131072) ? wk : (i < 196608) ? wv : wo;
  out[i] = f2bf(src[i & 65535]);
}

// ---------------- GroupNorm -> hnT [b][n][c] bf16 ----------------
__global__ __launch_bounds__(256)
void groupnorm_kernel(const float* __restrict__ x, const float* __restrict__ gamma,
                      const float* __restrict__ beta, unsigned short* __restrict__ hnT) {
  const int blk = blockIdx.x;        // b*32 + g
  const int b = blk >> 5, g = blk & 31;
  const int N = 4096;
  const float* xb = x + ((size_t)b * 256 + (size_t)g * 8) * N;
  const int tid = threadIdx.x;

  float s = 0.f, ss = 0.f;
  for (int c = 0; c < 8; ++c) {
    const float* xc = xb + (size_t)c * N;
    for (int i = tid; i < N; i += 256) { float v = xc[i]; s += v; ss += v * v; }
  }
  __shared__ float rs[4], rss[4];
  for (int m = 1; m <= 32; m <<= 1) { s += __shfl_xor(s, m); ss += __shfl_xor(ss, m); }
  const int lane = tid & 63, wid = tid >> 6;
  if (lane == 0) { rs[wid] = s; rss[wid] = ss; }
  __syncthreads();
  s  = rs[0] + rs[1] + rs[2] + rs[3];
  ss = rss[0] + rss[1] + rss[2] + rss[3];
  const float mean = s * (1.f / 32768.f);
  const float var  = ss * (1.f / 32768.f) - mean * mean;
  const float rstd = rsqrtf(var + 1e-6f);

  float gk[8], bk2[8];
  #pragma unroll
  for (int c = 0; c < 8; ++c) {
    float ga = gamma[g * 8 + c] * rstd;
    gk[c]  = ga;
    bk2[c] = beta[g * 8 + c] - mean * ga;
  }
  unsigned short* outp = hnT + (size_t)b * 256 * N + g * 8;
  for (int i = tid; i < N; i += 256) {
    union { unsigned short u[8]; uint4 v; } pk;
    #pragma unroll
    for (int c = 0; c < 8; ++c) pk.u[c] = f2bf(xb[(size_t)c * N + i] * gk[c] + bk2[c]);
    *reinterpret_cast<uint4*>(outp + (size_t)i * 256) = pk.v;
  }
}

// ---------------- fused flash attention, block j-split x4, KVBLK=32 ----------------
// Grid (qtb=32, jh=4, z=4) = 512 blocks -> 2 blocks/CU (LDS 74240 B).
// Block: 4 waves, wave w owns q-rows q0=qtb*128+w*32 .. +31; j in [jh*1024, +1024).
// LDS map (all reads verified <=2-way bank conflicts):
//   K bufs @0 + buf*16384:      32 rows x 512B, 32 slots, slot ^= (j&7)
//   V bufs @32768 + buf*16384:  256 rows x 64B,  4 slots, slot ^= s(c), s(r)=(r&3)^((r>>2)&3)
//   P @65536 + w*2048:          32 rows x 64B,   4 slots, slot ^= s(i)
//   sc @73728 + w*128 (32 f32)
// Partials (un-normalized o bf16, running m, sum l) -> global; merge kernel combines.
__global__ __launch_bounds__(256, 2)
void flash_attn(const unsigned short* __restrict__ Qt,
                const unsigned short* __restrict__ Kt,
                const unsigned short* __restrict__ Vp,
                unsigned short* __restrict__ Opart, float* __restrict__ mpart,
                float* __restrict__ lpart) {
  __shared__ alignas(1024) unsigned char lds[74240];
  const int tid = threadIdx.x, lane = tid & 63, w = tid >> 6;
  const int hig = lane >> 4, l15 = lane & 15;
  const int qtb = blockIdx.x, jh = blockIdx.y, z = blockIdx.z;
  const size_t zoff = (size_t)z * 1048576;
  const unsigned short* Qz = Qt + zoff;
  const unsigned short* Kz = Kt + zoff;
  const unsigned short* Vz = Vp + zoff;
  const int q0 = qtb * 128 + w * 32;
  const int jb0 = jh * 1024;
  const int sI = (l15 & 3) ^ ((l15 >> 2) & 3);  // row-slot swizzle (period 16)

  // Q fragments: qfr[qf][ks], B-operand (l15 = q-col, hig = c-subgroup)
  bf16x8 qfr[2][8];
  #pragma unroll
  for (int qf = 0; qf < 2; ++qf)
    #pragma unroll
    for (int ks = 0; ks < 8; ++ks)
      qfr[qf][ks] = *reinterpret_cast<const bf16x8*>(
          Qz + (size_t)(q0 + qf * 16 + l15) * 256 + ks * 32 + hig * 8);

  unsigned char* Pw = lds + 65536 + w * 2048;
  float* scp = (float*)(lds + 73728 + w * 128);

  // staging source pointers (t=0); K advances 8192 ushorts/t, V 32/t
  const unsigned short* pK[4];
  const unsigned short* pV[4];
  #pragma unroll
  for (int g = 0; g < 4; ++g) {
    const int jr = w * 8 + g * 2 + (lane >> 5);
    pK[g] = Kz + (size_t)(jb0 + jr) * 256 + (((lane & 31) ^ (jr & 7)) << 3);
    const int cV = w * 64 + g * 16 + (lane >> 2);
    const int sV = (cV & 3) ^ ((cV >> 2) & 3);
    pV[g] = Vz + (size_t)cV * 4096 + jb0 + (((lane & 3) ^ sV) << 3);
  }

  auto stage = [&](int d, int t) {
    unsigned char* Kd = lds + d * 16384 + w * 4096;
    unsigned char* Vd = lds + 32768 + d * 16384 + w * 4096;
    #pragma unroll
    for (int g = 0; g < 4; ++g) gload16(pK[g] + (size_t)t * 8192, Kd + g * 1024);
    #pragma unroll
    for (int g = 0; g < 4; ++g) gload16(pV[g] + (size_t)t * 32, Vd + g * 1024);
  };

  f32x4 o0[16] = {}, o1[16] = {};
  float mr0 = -1e30f, mr1 = -1e30f, l0 = 0.f, l1 = 0.f;

  stage(0, 0);
  for (int t = 0; t < 32; ++t) {
    asm volatile("s_waitcnt vmcnt(0)" ::: "memory");
    __builtin_amdgcn_s_barrier();
    __builtin_amdgcn_sched_barrier(0);
    const int cur = t & 1;
    if (t + 1 < 32) stage(cur ^ 1, t + 1);

    const unsigned char* Kb = lds + cur * 16384;
    const unsigned char* Vb = lds + 32768 + cur * 16384;

    // QK^T swapped: sA[jf][qf] rows j=jf*16+4hig+e, col q=l15
    f32x4 sA[2][2] = {};
    #pragma unroll
    for (int ks = 0; ks < 8; ++ks) {
      #pragma unroll
      for (int jf = 0; jf < 2; ++jf) {
        const int jl = jf * 16 + l15;
        bf16x8 kf = *reinterpret_cast<const bf16x8*>(
            Kb + jl * 512 + (((4 * ks + hig) ^ (jl & 7)) << 4));
        sA[jf][0] = __builtin_amdgcn_mfma_f32_16x16x32_bf16(kf, qfr[0][ks], sA[jf][0], 0, 0, 0);
        sA[jf][1] = __builtin_amdgcn_mfma_f32_16x16x32_bf16(kf, qfr[1][ks], sA[jf][1], 0, 0, 0);
      }
    }
    float tm0 = -1e30f, tm1 = -1e30f;
    #pragma unroll
    for (int jf = 0; jf < 2; ++jf) {
      sA[jf][0] *= 0.0625f; sA[jf][1] *= 0.0625f;
      #pragma unroll
      for (int e = 0; e < 4; ++e) {
        tm0 = fmaxf(tm0, sA[jf][0][e]);
        tm1 = fmaxf(tm1, sA[jf][1][e]);
      }
    }
    tm0 = fmaxf(tm0, __shfl_xor(tm0, 16)); tm0 = fmaxf(tm0, __shfl_xor(tm0, 32));
    tm1 = fmaxf(tm1, __shfl_xor(tm1, 16)); tm1 = fmaxf(tm1, __shfl_xor(tm1, 32));
    // defer-rescale: only when running max grows (keeps P <= 1)
    if (__any((tm0 > mr0) || (tm1 > mr1))) {
      const float mn0 = fmaxf(mr0, tm0), mn1 = fmaxf(mr1, tm1);
      const float s0 = __expf(mr0 - mn0), s1 = __expf(mr1 - mn1);
      l0 *= s0; l1 *= s1;
      if (hig == 0) { scp[l15] = s0; scp[16 + l15] = s1; }
      f32x4 sv0 = *reinterpret_cast<f32x4*>(scp + hig * 4);
      f32x4 sv1 = *reinterpret_cast<f32x4*>(scp + 16 + hig * 4);
      #pragma unroll
      for (int nf = 0; nf < 16; ++nf) { o0[nf] *= sv0; o1[nf] *= sv1; }
      mr0 = mn0; mr1 = mn1;
    }
    float ts0 = 0.f, ts1 = 0.f;
    #pragma unroll
    for (int jf = 0; jf < 2; ++jf) {
      const int so = (((2 * jf + (hig >> 1)) ^ sI) << 4) + ((hig & 1) << 3);
      {
        float p0 = __expf(sA[jf][0][0] - mr0), p1 = __expf(sA[jf][0][1] - mr0);
        float p2 = __expf(sA[jf][0][2] - mr0), p3 = __expf(sA[jf][0][3] - mr0);
        ts0 += (p0 + p1) + (p2 + p3);
        uint2 pk; pk.x = pack2(p0, p1); pk.y = pack2(p2, p3);
        *reinterpret_cast<uint2*>(Pw + l15 * 64 + so) = pk;
      }
      {
        float p0 = __expf(sA[jf][1][0] - mr1), p1 = __expf(sA[jf][1][1] - mr1);
        float p2 = __expf(sA[jf][1][2] - mr1), p3 = __expf(sA[jf][1][3] - mr1);
        ts1 += (p0 + p1) + (p2 + p3);
        uint2 pk; pk.x = pack2(p0, p1); pk.y = pack2(p2, p3);
        *reinterpret_cast<uint2*>(Pw + (16 + l15) * 64 + so) = pk;
      }
    }
    ts0 += __shfl_xor(ts0, 16); ts0 += __shfl_xor(ts0, 32); l0 += ts0;
    ts1 += __shfl_xor(ts1, 16); ts1 += __shfl_xor(ts1, 32); l1 += ts1;
    // PV: A = P rows i, B = V cols c, k = 32 j (one MFMA per (qf,nf))
    bf16x8 pa0 = *reinterpret_cast<const bf16x8*>(Pw + l15 * 64 + ((hig ^ sI) << 4));
    bf16x8 pa1 = *reinterpret_cast<const bf16x8*>(Pw + (16 + l15) * 64 + ((hig ^ sI) << 4));
    #pragma unroll
    for (int nf = 0; nf < 16; ++nf) {
      const int c = nf * 16 + l15;
      bf16x8 vb = *reinterpret_cast<const bf16x8*>(Vb + c * 64 + ((hig ^ sI) << 4));
      o0[nf] = __builtin_amdgcn_mfma_f32_16x16x32_bf16(pa0, vb, o0[nf], 0, 0, 0);
      o1[nf] = __builtin_amdgcn_mfma_f32_16x16x32_bf16(pa1, vb, o1[nf], 0, 0, 0);
    }
  }

  // epilogue: write un-normalized partials (bf16) + m,l for the merge kernel
  unsigned short* Ob = Opart + ((size_t)(jh * 4 + z) * 4096 + q0) * 256;
  #pragma unroll
  for (int qf = 0; qf < 2; ++qf)
    #pragma unroll
    for (int nf = 0; nf < 16; ++nf)
      #pragma unroll
      for (int e = 0; e < 4; ++e) {
        const int row = qf * 16 + 4 * hig + e;
        Ob[(size_t)row * 256 + nf * 16 + l15] = f2bf((qf == 0) ? o0[nf][e] : o1[nf][e]);
      }
  if (hig == 0) {
    const size_t mb = (size_t)(jh * 4 + z) * 4096 + q0;
    mpart[mb + l15] = mr0; mpart[mb + 16 + l15] = mr1;
    lpart[mb + l15] = l0;  lpart[mb + 16 + l15] = l1;
  }
}

// ---------------- merge the four j-quarters -> Ht bf16 ----------------
__global__ __launch_bounds__(256)
void flash_merge(const unsigned short* __restrict__ Opart, const float* __restrict__ mpart,
                 const float* __restrict__ lpart, unsigned short* __restrict__ Ht) {
  const int t = threadIdx.x;
  const int r = blockIdx.x * 4 + (t >> 6);   // r = z*4096 + n, in [0,16384)
  const int c = (t & 63) * 4;
  const int z = r >> 12, n = r & 4095;
  float mv[4], lv[4];
  float M = -1e30f;
  #pragma unroll
  for (int h = 0; h < 4; ++h) {
    const int idx = (h * 4 + z) * 4096 + n;
    mv[h] = mpart[idx]; lv[h] = lpart[idx];
    M = fmaxf(M, mv[h]);
  }
  float den = 0.f, a[4];
  #pragma unroll
  for (int h = 0; h < 4; ++h) { a[h] = __expf(mv[h] - M); den += lv[h] * a[h]; }
  const float inv = 1.f / den;
  float acc[4] = {};
  #pragma unroll
  for (int h = 0; h < 4; ++h) {
    ushort4 v = *reinterpret_cast<const ushort4*>(
        Opart + ((size_t)((h * 4 + z) * 4096 + n)) * 256 + c);
    acc[0] += bf2f(v.x) * a[h]; acc[1] += bf2f(v.y) * a[h];
    acc[2] += bf2f(v.z) * a[h]; acc[3] += bf2f(v.w) * a[h];
  }
  ushort4 pk;
  pk.x = f2bf(acc[0] * inv); pk.y = f2bf(acc[1] * inv);
  pk.z = f2bf(acc[2] * inv); pk.w = f2bf(acc[3] * inv);
  *reinterpret_cast<ushort4*>(Ht + (size_t)r * 256 + c) = pk;
}

// ---------------- 128x128 MFMA GEMM, A [M][K] bf16, B [N][K] bf16 ----------------
enum { MODE_T = 0, MODE_NAT = 1, MODE_OUT = 2 };

template<int MODE>
__global__ __launch_bounds__(256)
void gemm128(const unsigned short* __restrict__ A, long aStrideZ,
             const unsigned short* __restrict__ B, long bStrideZ,
             void* __restrict__ Out, long oStrideZ,
             const float* __restrict__ bias,
             const float* __restrict__ resid, long rStrideZ,
             int M, int N, int K, float scale) {
  __shared__ alignas(1024) unsigned char lds[32768];  // [buf][A 8K | B 8K]
  const int tid  = threadIdx.x;
  const int lane = tid & 63;
  const int hi   = lane >> 4;
  const int l15  = lane & 15;
  const int wid  = tid >> 6;
  const int wm = wid >> 1, wn = wid & 1;
  const int z  = blockIdx.z;
  const int m0 = blockIdx.y * 128;
  const int n0 = blockIdx.x * 128;
  const unsigned short* Az = A + (size_t)z * aStrideZ;
  const unsigned short* Bz = B + (size_t)z * bStrideZ;

  const int c0 = wid * 2, c1 = wid * 2 + 1;
  const int rr = lane >> 2;
  const int qs = (lane & 3) ^ ((lane >> 3) & 3);
  const unsigned short* pa0 = Az + (size_t)(m0 + c0 * 16 + rr) * K + qs * 8;
  const unsigned short* pa1 = Az + (size_t)(m0 + c1 * 16 + rr) * K + qs * 8;
  const unsigned short* pb0 = Bz + (size_t)(n0 + c0 * 16 + rr) * K + qs * 8;
  const unsigned short* pb1 = Bz + (size_t)(n0 + c1 * 16 + rr) * K + qs * 8;
  unsigned char* lA0 = lds + c0 * 1024;
  unsigned char* lA1 = lds + c1 * 1024;
  unsigned char* lB0 = lds + 8192 + c0 * 1024;
  unsigned char* lB1 = lds + 8192 + c1 * 1024;

  const int slot = hi ^ ((l15 >> 1) & 3);
  int roffA[4], roffB[4];
  #pragma unroll
  for (int t = 0; t < 4; ++t) {
    roffA[t] = (wm * 64 + t * 16 + l15) * 64 + slot * 16;
    roffB[t] = 8192 + (wn * 64 + t * 16 + l15) * 64 + slot * 16;
  }

  f32x4 acc[4][4] = {};

  const int nk = K >> 5;
  gload16(pa0, lA0); gload16(pa1, lA1);
  gload16(pb0, lB0); gload16(pb1, lB1);
  __syncthreads();

  int cur = 0;
  for (int kt = 0; kt < nk; ++kt) {
    if (kt + 1 < nk) {
      const size_t ko = (size_t)(kt + 1) * 32;
      const int bo = (cur ^ 1) * 16384;
      gload16(pa0 + ko, lA0 + bo); gload16(pa1 + ko, lA1 + bo);
      gload16(pb0 + ko, lB0 + bo); gload16(pb1 + ko, lB1 + bo);
    }
    const unsigned char* base = lds + cur * 16384;
    bf16x8 af[4], bfr[4];
    #pragma unroll
    for (int t = 0; t < 4; ++t) {
      af[t]  = *reinterpret_cast<const bf16x8*>(base + roffA[t]);
      bfr[t] = *reinterpret_cast<const bf16x8*>(base + roffB[t]);
    }
    #pragma unroll
    for (int mt = 0; mt < 4; ++mt)
      #pragma unroll
      for (int nt = 0; nt < 4; ++nt)
        acc[mt][nt] = __builtin_amdgcn_mfma_f32_16x16x32_bf16(af[mt], bfr[nt], acc[mt][nt], 0, 0, 0);
    __syncthreads();
    cur ^= 1;
  }

  const int gmb = m0 + wm * 64;
  const int gnb = n0 + wn * 64;
  if constexpr (MODE == MODE_T) {
    unsigned short* O = (unsigned short*)Out + (size_t)z * oStrideZ;
    #pragma unroll
    for (int mt = 0; mt < 4; ++mt) {
      const int gm0 = gmb + mt * 16 + 4 * hi;
      const float b0 = bias[gm0], b1 = bias[gm0 + 1], b2 = bias[gm0 + 2], b3 = bias[gm0 + 3];
      #pragma unroll
      for (int nt = 0; nt < 4; ++nt) {
        const int gn = gnb + nt * 16 + l15;
        ushort4 pk;
        pk.x = f2bf(acc[mt][nt][0] + b0);
        pk.y = f2bf(acc[mt][nt][1] + b1);
        pk.z = f2bf(acc[mt][nt][2] + b2);
        pk.w = f2bf(acc[mt][nt][3] + b3);
        *reinterpret_cast<ushort4*>(O + (size_t)gn * M + gm0) = pk;
      }
    }
  } else if constexpr (MODE == MODE_NAT) {
    unsigned short* O = (unsigned short*)Out + (size_t)z * oStrideZ;
    #pragma unroll
    for (int mt = 0; mt < 4; ++mt) {
      const int gm0 = gmb + mt * 16 + 4 * hi;
      #pragma unroll
      for (int nt = 0; nt < 4; ++nt) {
        const int gn = gnb + nt * 16 + l15;
        #pragma unroll
        for (int e = 0; e < 4; ++e) {
          float v = acc[mt][nt][e] * scale + (bias ? bias[gm0 + e] : 0.f);
          O[(size_t)(gm0 + e) * N + gn] = f2bf(v);
        }
      }
    }
  } else {
    float* O = (float*)Out + (size_t)z * oStrideZ;
    const float* R = resid + (size_t)z * rStrideZ;
    #pragma unroll
    for (int mt = 0; mt < 4; ++mt) {
      const int gm0 = gmb + mt * 16 + 4 * hi;
      #pragma unroll
      for (int nt = 0; nt < 4; ++nt) {
        const int gn = gnb + nt * 16 + l15;
        #pragma unroll
        for (int e = 0; e < 4; ++e) {
          size_t idx = (size_t)(gm0 + e) * N + gn;
          O[idx] = acc[mt][nt][e] + bias[gm0 + e] + R[idx];
        }
      }
    }
  }
}

__global__ void ws_too_small(float* out, float v) {
  if (threadIdx.x == 0 && blockIdx.x == 0) out[0] = v;
}

extern "C" void kernel_launch(void* const* d_in, const int* in_sizes, int n_in,
                              void* d_out, int out_size, void* d_ws, size_t ws_size,
                              hipStream_t stream) {
  const float* x     = (const float*)d_in[0];
  const float* gamma = (const float*)d_in[1];
  const float* beta  = (const float*)d_in[2];
  const float* Wq    = (const float*)d_in[3];
  const float* bq    = (const float*)d_in[4];
  const float* Wk    = (const float*)d_in[5];
  const float* bk    = (const float*)d_in[6];
  const float* Wv    = (const float*)d_in[7];
  const float* bv    = (const float*)d_in[8];
  const float* Wo    = (const float*)d_in[9];
  const float* bo    = (const float*)d_in[10];
  float* out = (float*)d_out;

  unsigned char* ws = (unsigned char*)d_ws;
  unsigned short* WB    = (unsigned short*)(ws);             // [4][256][256] bf16 (q,k,v,o)
  unsigned short* hnT   = (unsigned short*)(ws + 524288);    // [4][4096][256]
  float*          mpart = (float*)(ws + 524288);             // [4][4][4096] (reuses hnT after projections)
  float*          lpart = (float*)(ws + 786432);             // [4][4][4096]
  unsigned short* Qt    = (unsigned short*)(ws + 8912896);   // [4][4096][256]
  unsigned short* Kt    = (unsigned short*)(ws + 17301504);  // [4][4096][256]
  unsigned short* V     = (unsigned short*)(ws + 25690112);  // [4][256][4096]
  unsigned short* Ht    = (unsigned short*)(ws + 34078720);  // [4][4096][256]
  unsigned short* Opart = (unsigned short*)(ws + 42467328);  // [16][4096][256] bf16

  if (ws_size < 76283904) {
    hipMemsetAsync(d_out, 0, (size_t)out_size * 4, stream);
    ws_too_small<<<1, 64, 0, stream>>>(out, (float)ws_size);
    return;
  }

  prep_weights<<<1024, 256, 0, stream>>>(Wq, Wk, Wv, Wo, WB);
  groupnorm_kernel<<<128, 256, 0, stream>>>(x, gamma, beta, hnT);

  // QKV projections: M=256 (c_out), N=4096 (pixels), K=256 (c_in); z = batch
  gemm128<MODE_T><<<dim3(32, 2, 4), 256, 0, stream>>>(
      WB, 0, hnT, 1048576, Qt, 1048576, bq, nullptr, 0, 256, 4096, 256, 1.f);
  gemm128<MODE_T><<<dim3(32, 2, 4), 256, 0, stream>>>(
      WB + 65536, 0, hnT, 1048576, Kt, 1048576, bk, nullptr, 0, 256, 4096, 256, 1.f);
  gemm128<MODE_NAT><<<dim3(32, 2, 4), 256, 0, stream>>>(
      WB + 131072, 0, hnT, 1048576, V, 1048576, bv, nullptr, 0, 256, 4096, 256, 1.f);

  // fused attention, j split 4-way across blocks; then merge
  flash_attn<<<dim3(32, 4, 4), 256, 0, stream>>>(Qt, Kt, V, Opart, mpart, lpart);
  flash_merge<<<4096, 256, 0, stream>>>(Opart, mpart, lpart, Ht);

  // out[co][n] = sum_c Wo[co][c] * Ht[n][c] + bo[co] + x;  M=256, N=4096, K=256
  gemm128<MODE_OUT><<<dim3(32, 2, 4), 256, 0, stream>>>(
      WB + 196608, 0, Ht, 1048576, out, 1048576, bo, x, 1048576, 256, 4096, 256, 1.f);
}

// Round 9
// 187.833 us; speedup vs baseline: 1.5950x; 1.3240x over previous
//
#include <hip/hip_runtime.h>

typedef __attribute__((ext_vector_type(4))) float f32x4;
typedef __attribute__((ext_vector_type(8))) __bf16 bf16x8;

__device__ __forceinline__ unsigned short f2bf(float f) {
  unsigned int u = __float_as_uint(f);
  u += 0x7FFFu + ((u >> 16) & 1u);
  return (unsigned short)(u >> 16);
}
__device__ __forceinline__ unsigned int pack2(float a, float b) {
  return (unsigned int)f2bf(a) | ((unsigned int)f2bf(b) << 16);
}
__device__ __forceinline__ float bf2f(unsigned short u) {
  return __uint_as_float(((unsigned int)u) << 16);
}
__device__ __forceinline__ float ex2(float x) {
  return __builtin_amdgcn_exp2f(x);   // native v_exp_f32 (base-2)
}

__device__ __forceinline__ void gload16(const void* g, void* l) {
  __builtin_amdgcn_global_load_lds(
      (const __attribute__((address_space(1))) void*)g,
      (__attribute__((address_space(3))) void*)l, 16, 0, 0);
}

#define QSCALE 0.09016844005555897f  /* (1/16) * log2(e) */

// ---------------- weight fp32 -> bf16 ----------------
__global__ __launch_bounds__(256)
void prep_weights(const float* __restrict__ wq, const float* __restrict__ wk,
                  const float* __restrict__ wv, const float* __restrict__ wo,
                  unsigned short* __restrict__ out) {
  int i = blockIdx.x * 256 + threadIdx.x;  // 4 * 65536 total
  const float* src = (i < 65536) ? wq : (i < 131072) ? wk : (i < 196608) ? wv : wo;
  out[i] = f2bf(src[i & 65535]);
}

// ---------------- GroupNorm -> hnT [b][n][c] bf16 ----------------
__global__ __launch_bounds__(512)
void groupnorm_kernel(const float* __restrict__ x, const float* __restrict__ gamma,
                      const float* __restrict__ beta, unsigned short* __restrict__ hnT) {
  const int blk = blockIdx.x;        // b*32 + g
  const int b = blk >> 5, g = blk & 31;
  const int N = 4096;
  const float* xb = x + ((size_t)b * 256 + (size_t)g * 8) * N;
  const int tid = threadIdx.x;

  float s = 0.f, ss = 0.f;
  for (int c = 0; c < 8; ++c) {
    const float* xc = xb + (size_t)c * N;
    for (int i = tid; i < N; i += 512) { float v = xc[i]; s += v; ss += v * v; }
  }
  __shared__ float rs[8], rss[8];
  for (int m = 1; m <= 32; m <<= 1) { s += __shfl_xor(s, m); ss += __shfl_xor(ss, m); }
  const int lane = tid & 63, wid = tid >> 6;
  if (lane == 0) { rs[wid] = s; rss[wid] = ss; }
  __syncthreads();
  s = 0.f; ss = 0.f;
  #pragma unroll
  for (int i = 0; i < 8; ++i) { s += rs[i]; ss += rss[i]; }
  const float mean = s * (1.f / 32768.f);
  const float var  = ss * (1.f / 32768.f) - mean * mean;
  const float rstd = rsqrtf(var + 1e-6f);

  float gk[8], bk2[8];
  #pragma unroll
  for (int c = 0; c < 8; ++c) {
    float ga = gamma[g * 8 + c] * rstd;
    gk[c]  = ga;
    bk2[c] = beta[g * 8 + c] - mean * ga;
  }
  unsigned short* outp = hnT + (size_t)b * 256 * N + g * 8;
  for (int i = tid; i < N; i += 512) {
    union { unsigned short u[8]; uint4 v; } pk;
    #pragma unroll
    for (int c = 0; c < 8; ++c) pk.u[c] = f2bf(xb[(size_t)c * N + i] * gk[c] + bk2[c]);
    *reinterpret_cast<uint4*>(outp + (size_t)i * 256) = pk.v;
  }
}

// ---------------- fused QKV projection ----------------
// Grid (64 n-tiles, 4 z), 256 threads, 3 blocks/CU (LDS 48KB).
// B = hnT tile [64 n][256 k] staged ONCE (rows 512B, 32 slots, slot ^= (r&7)).
// A = weights, 6 tiles (q,k,v x 2 m-halves) of [128 m][256 k], streamed through
// a double-buffered 8KB pipe in 48 steps (gemm128's validated staging).
// Outputs: Qt,Kt [n][m] bf16 (Q scaled by QSCALE incl bias); V [m][n] bf16.
__global__ __launch_bounds__(256, 3)
void qkv_fused(const unsigned short* __restrict__ WB,
               const unsigned short* __restrict__ hnT,
               const float* __restrict__ bq, const float* __restrict__ bk,
               const float* __restrict__ bv,
               unsigned short* __restrict__ Qt, unsigned short* __restrict__ Kt,
               unsigned short* __restrict__ Vp) {
  __shared__ alignas(1024) unsigned char lds[49152];  // B 32KB @0, A dbuf 2x8KB @32768
  const int tid = threadIdx.x, lane = tid & 63, w = tid >> 6;
  const int hig = lane >> 4, l15 = lane & 15;
  const int z = blockIdx.y, nt = blockIdx.x;
  const int n0 = nt * 64;
  const size_t zoff = (size_t)z * 1048576;
  const unsigned short* hnB = hnT + zoff + (size_t)n0 * 256;

  // stage B tile (64 rows x 512B): 8 passes x 256 lanes x 16B
  #pragma unroll
  for (int p = 0; p < 8; ++p) {
    const int idx = p * 256 + tid;
    const int r = idx >> 5, sl = idx & 31;
    gload16(hnB + (size_t)r * 256 + ((sl ^ (r & 7)) << 3), lds + idx * 16);
  }

  // A staging (step s: tile sel=s>>3, kt=s&7)
  const int qs = (lane & 3) ^ ((lane >> 3) & 3);
  const int ar = tid >> 2, asq = tid & 3;
  auto stageA = [&](int d, int s) {
    const unsigned short* base = WB + (s >> 3) * 32768 + (s & 7) * 32 + qs * 8;
    unsigned char* dst = lds + 32768 + d * 8192;
    gload16(base + (size_t)ar * 256,        dst + ar * 64 + asq * 16);
    gload16(base + (size_t)(ar + 64) * 256, dst + (ar + 64) * 64 + asq * 16);
  };

  const int aslot = hig ^ ((l15 >> 1) & 3);
  f32x4 acc[2][4] = {};

  stageA(0, 0);
  __syncthreads();  // drains B + A(0)

  for (int s = 0; s < 48; ++s) {
    const int d = s & 1;
    if (s + 1 < 48) stageA(d ^ 1, s + 1);
    const int kt = s & 7;
    // A frags: rows w*32 + mf*16 + l15
    bf16x8 af[2];
    #pragma unroll
    for (int mf = 0; mf < 2; ++mf)
      af[mf] = *reinterpret_cast<const bf16x8*>(
          lds + 32768 + d * 8192 + (w * 32 + mf * 16 + l15) * 64 + aslot * 16);
    // B frags: rows nf*16 + l15, source slot kt*4+hig
    #pragma unroll
    for (int nf = 0; nf < 4; ++nf) {
      const int rb = nf * 16 + l15;
      bf16x8 bfr = *reinterpret_cast<const bf16x8*>(
          lds + rb * 512 + (((kt * 4 + hig) ^ (rb & 7)) << 4));
      acc[0][nf] = __builtin_amdgcn_mfma_f32_16x16x32_bf16(af[0], bfr, acc[0][nf], 0, 0, 0);
      acc[1][nf] = __builtin_amdgcn_mfma_f32_16x16x32_bf16(af[1], bfr, acc[1][nf], 0, 0, 0);
    }
    if (kt == 7) {  // epilogue for tile sel
      const int sel = s >> 3, wsel = sel >> 1, mh = sel & 1;
      #pragma unroll
      for (int mf = 0; mf < 2; ++mf) {
        const int gm0 = mh * 128 + w * 32 + mf * 16 + 4 * hig;
        #pragma unroll
        for (int nf = 0; nf < 4; ++nf) {
          const int n = n0 + nf * 16 + l15;
          if (wsel == 0) {
            ushort4 pk;
            pk.x = f2bf((acc[mf][nf][0] + bq[gm0])     * QSCALE);
            pk.y = f2bf((acc[mf][nf][1] + bq[gm0 + 1]) * QSCALE);
            pk.z = f2bf((acc[mf][nf][2] + bq[gm0 + 2]) * QSCALE);
            pk.w = f2bf((acc[mf][nf][3] + bq[gm0 + 3]) * QSCALE);
            *reinterpret_cast<ushort4*>(Qt + zoff + (size_t)n * 256 + gm0) = pk;
          } else if (wsel == 1) {
            ushort4 pk;
            pk.x = f2bf(acc[mf][nf][0] + bk[gm0]);
            pk.y = f2bf(acc[mf][nf][1] + bk[gm0 + 1]);
            pk.z = f2bf(acc[mf][nf][2] + bk[gm0 + 2]);
            pk.w = f2bf(acc[mf][nf][3] + bk[gm0 + 3]);
            *reinterpret_cast<ushort4*>(Kt + zoff + (size_t)n * 256 + gm0) = pk;
          } else {
            #pragma unroll
            for (int e = 0; e < 4; ++e)
              Vp[zoff + (size_t)(gm0 + e) * 4096 + n] = f2bf(acc[mf][nf][e] + bv[gm0 + e]);
          }
          acc[mf][nf] = f32x4{0.f, 0.f, 0.f, 0.f};
        }
      }
    }
    __syncthreads();
  }
}

// ---------------- fused flash attention, block j-split x4, KVBLK=32 ----------------
// (base-2 softmax: Qt carries 1/16*log2e; exp2 throughout)
__global__ __launch_bounds__(256, 2)
void flash_attn(const unsigned short* __restrict__ Qt,
                const unsigned short* __restrict__ Kt,
                const unsigned short* __restrict__ Vp,
                unsigned short* __restrict__ Opart, float* __restrict__ mpart,
                float* __restrict__ lpart) {
  __shared__ alignas(1024) unsigned char lds[74240];
  const int tid = threadIdx.x, lane = tid & 63, w = tid >> 6;
  const int hig = lane >> 4, l15 = lane & 15;
  const int qtb = blockIdx.x, jh = blockIdx.y, z = blockIdx.z;
  const size_t zoff = (size_t)z * 1048576;
  const unsigned short* Qz = Qt + zoff;
  const unsigned short* Kz = Kt + zoff;
  const unsigned short* Vz = Vp + zoff;
  const int q0 = qtb * 128 + w * 32;
  const int jb0 = jh * 1024;
  const int sI = (l15 & 3) ^ ((l15 >> 2) & 3);  // row-slot swizzle (period 16)

  bf16x8 qfr[2][8];
  #pragma unroll
  for (int qf = 0; qf < 2; ++qf)
    #pragma unroll
    for (int ks = 0; ks < 8; ++ks)
      qfr[qf][ks] = *reinterpret_cast<const bf16x8*>(
          Qz + (size_t)(q0 + qf * 16 + l15) * 256 + ks * 32 + hig * 8);

  unsigned char* Pw = lds + 65536 + w * 2048;
  float* scp = (float*)(lds + 73728 + w * 128);

  const unsigned short* pK[4];
  const unsigned short* pV[4];
  #pragma unroll
  for (int g = 0; g < 4; ++g) {
    const int jr = w * 8 + g * 2 + (lane >> 5);
    pK[g] = Kz + (size_t)(jb0 + jr) * 256 + (((lane & 31) ^ (jr & 7)) << 3);
    const int cV = w * 64 + g * 16 + (lane >> 2);
    const int sV = (cV & 3) ^ ((cV >> 2) & 3);
    pV[g] = Vz + (size_t)cV * 4096 + jb0 + (((lane & 3) ^ sV) << 3);
  }

  auto stage = [&](int d, int t) {
    unsigned char* Kd = lds + d * 16384 + w * 4096;
    unsigned char* Vd = lds + 32768 + d * 16384 + w * 4096;
    #pragma unroll
    for (int g = 0; g < 4; ++g) gload16(pK[g] + (size_t)t * 8192, Kd + g * 1024);
    #pragma unroll
    for (int g = 0; g < 4; ++g) gload16(pV[g] + (size_t)t * 32, Vd + g * 1024);
  };

  f32x4 o0[16] = {}, o1[16] = {};
  float mr0 = -1e30f, mr1 = -1e30f, l0 = 0.f, l1 = 0.f;

  stage(0, 0);
  for (int t = 0; t < 32; ++t) {
    asm volatile("s_waitcnt vmcnt(0)" ::: "memory");
    __builtin_amdgcn_s_barrier();
    __builtin_amdgcn_sched_barrier(0);
    const int cur = t & 1;
    if (t + 1 < 32) stage(cur ^ 1, t + 1);

    const unsigned char* Kb = lds + cur * 16384;
    const unsigned char* Vb = lds + 32768 + cur * 16384;

    f32x4 sA[2][2] = {};
    #pragma unroll
    for (int ks = 0; ks < 8; ++ks) {
      #pragma unroll
      for (int jf = 0; jf < 2; ++jf) {
        const int jl = jf * 16 + l15;
        bf16x8 kf = *reinterpret_cast<const bf16x8*>(
            Kb + jl * 512 + (((4 * ks + hig) ^ (jl & 7)) << 4));
        sA[jf][0] = __builtin_amdgcn_mfma_f32_16x16x32_bf16(kf, qfr[0][ks], sA[jf][0], 0, 0, 0);
        sA[jf][1] = __builtin_amdgcn_mfma_f32_16x16x32_bf16(kf, qfr[1][ks], sA[jf][1], 0, 0, 0);
      }
    }
    float tm0 = -1e30f, tm1 = -1e30f;
    #pragma unroll
    for (int jf = 0; jf < 2; ++jf)
      #pragma unroll
      for (int e = 0; e < 4; ++e) {
        tm0 = fmaxf(tm0, sA[jf][0][e]);
        tm1 = fmaxf(tm1, sA[jf][1][e]);
      }
    tm0 = fmaxf(tm0, __shfl_xor(tm0, 16)); tm0 = fmaxf(tm0, __shfl_xor(tm0, 32));
    tm1 = fmaxf(tm1, __shfl_xor(tm1, 16)); tm1 = fmaxf(tm1, __shfl_xor(tm1, 32));
    if (__any((tm0 > mr0) || (tm1 > mr1))) {
      const float mn0 = fmaxf(mr0, tm0), mn1 = fmaxf(mr1, tm1);
      const float s0 = ex2(mr0 - mn0), s1 = ex2(mr1 - mn1);
      l0 *= s0; l1 *= s1;
      if (hig == 0) { scp[l15] = s0; scp[16 + l15] = s1; }
      f32x4 sv0 = *reinterpret_cast<f32x4*>(scp + hig * 4);
      f32x4 sv1 = *reinterpret_cast<f32x4*>(scp + 16 + hig * 4);
      #pragma unroll
      for (int nf = 0; nf < 16; ++nf) { o0[nf] *= sv0; o1[nf] *= sv1; }
      mr0 = mn0; mr1 = mn1;
    }
    float ts0 = 0.f, ts1 = 0.f;
    #pragma unroll
    for (int jf = 0; jf < 2; ++jf) {
      const int so = (((2 * jf + (hig >> 1)) ^ sI) << 4) + ((hig & 1) << 3);
      {
        float p0 = ex2(sA[jf][0][0] - mr0), p1 = ex2(sA[jf][0][1] - mr0);
        float p2 = ex2(sA[jf][0][2] - mr0), p3 = ex2(sA[jf][0][3] - mr0);
        ts0 += (p0 + p1) + (p2 + p3);
        uint2 pk; pk.x = pack2(p0, p1); pk.y = pack2(p2, p3);
        *reinterpret_cast<uint2*>(Pw + l15 * 64 + so) = pk;
      }
      {
        float p0 = ex2(sA[jf][1][0] - mr1), p1 = ex2(sA[jf][1][1] - mr1);
        float p2 = ex2(sA[jf][1][2] - mr1), p3 = ex2(sA[jf][1][3] - mr1);
        ts1 += (p0 + p1) + (p2 + p3);
        uint2 pk; pk.x = pack2(p0, p1); pk.y = pack2(p2, p3);
        *reinterpret_cast<uint2*>(Pw + (16 + l15) * 64 + so) = pk;
      }
    }
    ts0 += __shfl_xor(ts0, 16); ts0 += __shfl_xor(ts0, 32); l0 += ts0;
    ts1 += __shfl_xor(ts1, 16); ts1 += __shfl_xor(ts1, 32); l1 += ts1;
    bf16x8 pa0 = *reinterpret_cast<const bf16x8*>(Pw + l15 * 64 + ((hig ^ sI) << 4));
    bf16x8 pa1 = *reinterpret_cast<const bf16x8*>(Pw + (16 + l15) * 64 + ((hig ^ sI) << 4));
    #pragma unroll
    for (int nf = 0; nf < 16; ++nf) {
      const int c = nf * 16 + l15;
      bf16x8 vb = *reinterpret_cast<const bf16x8*>(Vb + c * 64 + ((hig ^ sI) << 4));
      o0[nf] = __builtin_amdgcn_mfma_f32_16x16x32_bf16(pa0, vb, o0[nf], 0, 0, 0);
      o1[nf] = __builtin_amdgcn_mfma_f32_16x16x32_bf16(pa1, vb, o1[nf], 0, 0, 0);
    }
  }

  unsigned short* Ob = Opart + ((size_t)(jh * 4 + z) * 4096 + q0) * 256;
  #pragma unroll
  for (int qf = 0; qf < 2; ++qf)
    #pragma unroll
    for (int nf = 0; nf < 16; ++nf)
      #pragma unroll
      for (int e = 0; e < 4; ++e) {
        const int row = qf * 16 + 4 * hig + e;
        Ob[(size_t)row * 256 + nf * 16 + l15] = f2bf((qf == 0) ? o0[nf][e] : o1[nf][e]);
      }
  if (hig == 0) {
    const size_t mb = (size_t)(jh * 4 + z) * 4096 + q0;
    mpart[mb + l15] = mr0; mpart[mb + 16 + l15] = mr1;
    lpart[mb + l15] = l0;  lpart[mb + 16 + l15] = l1;
  }
}

// ---------------- merge the four j-quarters -> Ht bf16 ----------------
__global__ __launch_bounds__(256)
void flash_merge(const unsigned short* __restrict__ Opart, const float* __restrict__ mpart,
                 const float* __restrict__ lpart, unsigned short* __restrict__ Ht) {
  const int t = threadIdx.x;
  const int r = blockIdx.x * 4 + (t >> 6);   // r = z*4096 + n, in [0,16384)
  const int c = (t & 63) * 4;
  const int z = r >> 12, n = r & 4095;
  float mv[4], lv[4];
  float M = -1e30f;
  #pragma unroll
  for (int h = 0; h < 4; ++h) {
    const int idx = (h * 4 + z) * 4096 + n;
    mv[h] = mpart[idx]; lv[h] = lpart[idx];
    M = fmaxf(M, mv[h]);
  }
  float den = 0.f, a[4];
  #pragma unroll
  for (int h = 0; h < 4; ++h) { a[h] = ex2(mv[h] - M); den += lv[h] * a[h]; }
  const float inv = 1.f / den;
  float acc[4] = {};
  #pragma unroll
  for (int h = 0; h < 4; ++h) {
    ushort4 v = *reinterpret_cast<const ushort4*>(
        Opart + ((size_t)((h * 4 + z) * 4096 + n)) * 256 + c);
    acc[0] += bf2f(v.x) * a[h]; acc[1] += bf2f(v.y) * a[h];
    acc[2] += bf2f(v.z) * a[h]; acc[3] += bf2f(v.w) * a[h];
  }
  ushort4 pk;
  pk.x = f2bf(acc[0] * inv); pk.y = f2bf(acc[1] * inv);
  pk.z = f2bf(acc[2] * inv); pk.w = f2bf(acc[3] * inv);
  *reinterpret_cast<ushort4*>(Ht + (size_t)r * 256 + c) = pk;
}

// ---------------- 128x128 MFMA GEMM (O-projection w/ residual) ----------------
__global__ __launch_bounds__(256)
void gemm_out(const unsigned short* __restrict__ A,
              const unsigned short* __restrict__ B, long bStrideZ,
              float* __restrict__ Out, long oStrideZ,
              const float* __restrict__ bias,
              const float* __restrict__ resid, long rStrideZ,
              int M, int N, int K) {
  __shared__ alignas(1024) unsigned char lds[32768];
  const int tid  = threadIdx.x;
  const int lane = tid & 63;
  const int hi   = lane >> 4;
  const int l15  = lane & 15;
  const int wid  = tid >> 6;
  const int wm = wid >> 1, wn = wid & 1;
  const int z  = blockIdx.z;
  const int m0 = blockIdx.y * 128;
  const int n0 = blockIdx.x * 128;
  const unsigned short* Az = A;
  const unsigned short* Bz = B + (size_t)z * bStrideZ;

  const int c0 = wid * 2, c1 = wid * 2 + 1;
  const int rr = lane >> 2;
  const int qs = (lane & 3) ^ ((lane >> 3) & 3);
  const unsigned short* pa0 = Az + (size_t)(m0 + c0 * 16 + rr) * K + qs * 8;
  const unsigned short* pa1 = Az + (size_t)(m0 + c1 * 16 + rr) * K + qs * 8;
  const unsigned short* pb0 = Bz + (size_t)(n0 + c0 * 16 + rr) * K + qs * 8;
  const unsigned short* pb1 = Bz + (size_t)(n0 + c1 * 16 + rr) * K + qs * 8;
  unsigned char* lA0 = lds + c0 * 1024;
  unsigned char* lA1 = lds + c1 * 1024;
  unsigned char* lB0 = lds + 8192 + c0 * 1024;
  unsigned char* lB1 = lds + 8192 + c1 * 1024;

  const int slot = hi ^ ((l15 >> 1) & 3);
  int roffA[4], roffB[4];
  #pragma unroll
  for (int t = 0; t < 4; ++t) {
    roffA[t] = (wm * 64 + t * 16 + l15) * 64 + slot * 16;
    roffB[t] = 8192 + (wn * 64 + t * 16 + l15) * 64 + slot * 16;
  }

  f32x4 acc[4][4] = {};

  const int nk = K >> 5;
  gload16(pa0, lA0); gload16(pa1, lA1);
  gload16(pb0, lB0); gload16(pb1, lB1);
  __syncthreads();

  int cur = 0;
  for (int kt = 0; kt < nk; ++kt) {
    if (kt + 1 < nk) {
      const size_t ko = (size_t)(kt + 1) * 32;
      const int bo = (cur ^ 1) * 16384;
      gload16(pa0 + ko, lA0 + bo); gload16(pa1 + ko, lA1 + bo);
      gload16(pb0 + ko, lB0 + bo); gload16(pb1 + ko, lB1 + bo);
    }
    const unsigned char* base = lds + cur * 16384;
    bf16x8 af[4], bfr[4];
    #pragma unroll
    for (int t = 0; t < 4; ++t) {
      af[t]  = *reinterpret_cast<const bf16x8*>(base + roffA[t]);
      bfr[t] = *reinterpret_cast<const bf16x8*>(base + roffB[t]);
    }
    #pragma unroll
    for (int mt = 0; mt < 4; ++mt)
      #pragma unroll
      for (int nt = 0; nt < 4; ++nt)
        acc[mt][nt] = __builtin_amdgcn_mfma_f32_16x16x32_bf16(af[mt], bfr[nt], acc[mt][nt], 0, 0, 0);
    __syncthreads();
    cur ^= 1;
  }

  const int gmb = m0 + wm * 64;
  const int gnb = n0 + wn * 64;
  float* O = Out + (size_t)z * oStrideZ;
  const float* R = resid + (size_t)z * rStrideZ;
  #pragma unroll
  for (int mt = 0; mt < 4; ++mt) {
    const int gm0 = gmb + mt * 16 + 4 * hi;
    #pragma unroll
    for (int nt = 0; nt < 4; ++nt) {
      const int gn = gnb + nt * 16 + l15;
      #pragma unroll
      for (int e = 0; e < 4; ++e) {
        size_t idx = (size_t)(gm0 + e) * N + gn;
        O[idx] = acc[mt][nt][e] + bias[gm0 + e] + R[idx];
      }
    }
  }
}

__global__ void ws_too_small(float* out, float v) {
  if (threadIdx.x == 0 && blockIdx.x == 0) out[0] = v;
}

extern "C" void kernel_launch(void* const* d_in, const int* in_sizes, int n_in,
                              void* d_out, int out_size, void* d_ws, size_t ws_size,
                              hipStream_t stream) {
  const float* x     = (const float*)d_in[0];
  const float* gamma = (const float*)d_in[1];
  const float* beta  = (const float*)d_in[2];
  const float* Wq    = (const float*)d_in[3];
  const float* bq    = (const float*)d_in[4];
  const float* Wk    = (const float*)d_in[5];
  const float* bk    = (const float*)d_in[6];
  const float* Wv    = (const float*)d_in[7];
  const float* bv    = (const float*)d_in[8];
  const float* Wo    = (const float*)d_in[9];
  const float* bo    = (const float*)d_in[10];
  float* out = (float*)d_out;

  unsigned char* ws = (unsigned char*)d_ws;
  unsigned short* WB    = (unsigned short*)(ws);             // [4][256][256] bf16 (q,k,v,o)
  unsigned short* hnT   = (unsigned short*)(ws + 524288);    // [4][4096][256]
  float*          mpart = (float*)(ws + 524288);             // [4][4][4096] (reuses hnT after projections)
  float*          lpart = (float*)(ws + 786432);             // [4][4][4096]
  unsigned short* Qt    = (unsigned short*)(ws + 8912896);   // [4][4096][256]
  unsigned short* Kt    = (unsigned short*)(ws + 17301504);  // [4][4096][256]
  unsigned short* V     = (unsigned short*)(ws + 25690112);  // [4][256][4096]
  unsigned short* Ht    = (unsigned short*)(ws + 34078720);  // [4][4096][256]
  unsigned short* Opart = (unsigned short*)(ws + 42467328);  // [16][4096][256] bf16

  if (ws_size < 76283904) {
    hipMemsetAsync(d_out, 0, (size_t)out_size * 4, stream);
    ws_too_small<<<1, 64, 0, stream>>>(out, (float)ws_size);
    return;
  }

  prep_weights<<<1024, 256, 0, stream>>>(Wq, Wk, Wv, Wo, WB);
  groupnorm_kernel<<<128, 512, 0, stream>>>(x, gamma, beta, hnT);

  // fused QKV projections (Q pre-scaled by 1/16*log2e)
  qkv_fused<<<dim3(64, 4), 256, 0, stream>>>(WB, hnT, bq, bk, bv, Qt, Kt, V);

  // fused attention (base-2 softmax), j split 4-way across blocks; then merge
  flash_attn<<<dim3(32, 4, 4), 256, 0, stream>>>(Qt, Kt, V, Opart, mpart, lpart);
  flash_merge<<<4096, 256, 0, stream>>>(Opart, mpart, lpart, Ht);

  // out[co][n] = sum_c Wo[co][c] * Ht[n][c] + bo[co] + x
  gemm_out<<<dim3(32, 2, 4), 256, 0, stream>>>(
      WB + 196608, Ht, 1048576, out, 1048576, bo, x, 1048576, 256, 4096, 256);
}